// Round 1
// baseline (66326.025 us; speedup 1.0000x reference)
//
#include <hip/hip_runtime.h>
#include <hip/hip_bf16.h>
#include <math.h>

// GRU_74758200754229: 2-layer GRU (B=128, T=1024, F=256, H=512) + final linear.
// Round 1 design: per-timestep kernel launches (graph-friendly, no grid sync),
// layer-pipelined (layer0 @ t=s and layer1 @ t=s-1 in the same launch),
// fp32 VALU compute, h/x tiles staged transposed in LDS, weights from L2.

#define T_LEN 1024
#define B_SZ  128
#define F_IN  256
#define H_SZ  512
#define PAD   33                       // 32 batch cols + 1 pad -> conflict-free

#define LDS_FLOATS ((H_SZ + H_SZ) * PAD)   // 33792 floats = 132 KB (max of A/B needs)

// Stage a [32 rows][K] global tile into LDS transposed as [K][32] (padded).
// Coalesced global reads (consecutive tid -> consecutive k), stride-PAD LDS
// writes (conflict-free).
template<int K>
__device__ __forceinline__ void stage_tile(float* __restrict__ dst,
                                           const float* __restrict__ src,
                                           long row_stride, bool zero)
{
  constexpr int total = 32 * K;
  for (int idx = threadIdx.x; idx < total; idx += 256) {
    int b = idx / K;          // K is a power of two -> shifts
    int k = idx & (K - 1);
    dst[k * PAD + b] = zero ? 0.f : src[(long)b * row_stride + k];
  }
}

__device__ __forceinline__ float sigm(float v) { return 1.f / (1.f + __expf(-v)); }

// Shared epilogue: gates + state update + store of h_new tile.
__device__ __forceinline__ void gru_epilogue(const float (&accg)[3][2],
                                             const float (&accx)[3][2],
                                             const float* __restrict__ bih,
                                             const float* __restrict__ bhh,
                                             const float* __restrict__ hL,
                                             int lb, int jA, int b0,
                                             float* __restrict__ hw)
{
  #pragma unroll
  for (int jj = 0; jj < 2; ++jj) {
    const int j = jA + jj;
    const float xr = accx[0][jj] + bih[j];
    const float xz = accx[1][jj] + bih[H_SZ + j];
    const float xn = accx[2][jj] + bih[2 * H_SZ + j];
    const float hr = accg[0][jj] + bhh[j];
    const float hz = accg[1][jj] + bhh[H_SZ + j];
    const float hn = accg[2][jj] + bhh[2 * H_SZ + j];
    const float r = sigm(xr + hr);
    const float z = sigm(xz + hz);
    const float n = tanhf(xn + r * hn);
    const float hp = hL[j * PAD + lb];            // zero-filled on first step
    hw[(long)(b0 + lb) * H_SZ + j] = (1.f - z) * n + z * hp;
  }
}

// Accumulate 2 j-rows x 3 gates over K from an LDS tile aL[k][32] against
// weight matrix W with row length RK, rows (g*H + jA + jj).
template<int K, int RK>
__device__ __forceinline__ void dot_block(float (&acc)[3][2],
                                          const float* __restrict__ aL,
                                          const float* __restrict__ W,
                                          int lb, int jA)
{
  #pragma unroll 2
  for (int k = 0; k < K; k += 4) {
    const float a0 = aL[(k + 0) * PAD + lb];
    const float a1 = aL[(k + 1) * PAD + lb];
    const float a2 = aL[(k + 2) * PAD + lb];
    const float a3 = aL[(k + 3) * PAD + lb];
    #pragma unroll
    for (int g = 0; g < 3; ++g) {
      #pragma unroll
      for (int jj = 0; jj < 2; ++jj) {
        const float4 w = *(const float4*)(W + (long)(g * H_SZ + jA + jj) * RK + k);
        acc[g][jj] = fmaf(w.x, a0, fmaf(w.y, a1, fmaf(w.z, a2, fmaf(w.w, a3, acc[g][jj]))));
      }
    }
  }
}

__global__ void __launch_bounds__(256)
gru_step(int s,
         const float* __restrict__ x,
         const float* __restrict__ Wih0, const float* __restrict__ Whh0,
         const float* __restrict__ bih0, const float* __restrict__ bhh0,
         const float* __restrict__ Wih1, const float* __restrict__ Whh1,
         const float* __restrict__ bih1, const float* __restrict__ bhh1,
         const float* __restrict__ h0_r, float* __restrict__ h0_w,
         const float* __restrict__ h1_r, float* __restrict__ h1_w)
{
  extern __shared__ float lds[];
  const int tid = threadIdx.x;
  const int lb  = tid & 31;       // batch lane within tile
  const int jg  = tid >> 5;       // 0..7 -> j-group (2 j each)

  if (blockIdx.x < 128) {
    // ---------------- layer 0 at time t = s ----------------
    if (s >= T_LEN) return;
    const int b0 = (blockIdx.x >> 5) * 32;
    const int j0 = (blockIdx.x & 31) * 16;
    float* hL = lds;
    float* xL = lds + H_SZ * PAD;
    stage_tile<H_SZ>(hL, h0_r + (long)b0 * H_SZ, H_SZ, s == 0);
    stage_tile<F_IN>(xL, x + ((long)b0 * T_LEN + s) * F_IN, (long)T_LEN * F_IN, false);
    __syncthreads();

    const int jA = j0 + jg * 2;
    float accg[3][2] = {{0.f,0.f},{0.f,0.f},{0.f,0.f}};
    float accx[3][2] = {{0.f,0.f},{0.f,0.f},{0.f,0.f}};
    dot_block<H_SZ, H_SZ>(accg, hL, Whh0, lb, jA);   // h @ W_hh0^T
    dot_block<F_IN, F_IN>(accx, xL, Wih0, lb, jA);   // x_t @ W_ih0^T
    gru_epilogue(accg, accx, bih0, bhh0, hL, lb, jA, b0, h0_w);
  } else {
    // ---------------- layer 1 at time t = s-1 ----------------
    if (s < 1) return;
    const int id = blockIdx.x - 128;
    const int b0 = (id >> 5) * 32;
    const int j0 = (id & 31) * 16;
    float* hL = lds;
    float* yL = lds + H_SZ * PAD;
    // h0_r holds layer-0 output of time s-1 (written by previous launch).
    stage_tile<H_SZ>(hL, h1_r + (long)b0 * H_SZ, H_SZ, s == 1);
    stage_tile<H_SZ>(yL, h0_r + (long)b0 * H_SZ, H_SZ, false);
    __syncthreads();

    const int jA = j0 + jg * 2;
    float accg[3][2] = {{0.f,0.f},{0.f,0.f},{0.f,0.f}};
    float accx[3][2] = {{0.f,0.f},{0.f,0.f},{0.f,0.f}};
    dot_block<H_SZ, H_SZ>(accg, hL, Whh1, lb, jA);   // h1 @ W_hh1^T
    dot_block<H_SZ, H_SZ>(accx, yL, Wih1, lb, jA);   // y0 @ W_ih1^T
    gru_epilogue(accg, accx, bih1, bhh1, hL, lb, jA, b0, h1_w);
  }
}

__global__ void __launch_bounds__(64)
final_linear(const float* __restrict__ h1,
             const float* __restrict__ wlin,
             const float* __restrict__ blin,
             float* __restrict__ out)
{
  const int b = blockIdx.x;
  const int lane = threadIdx.x;   // 64
  float acc = 0.f;
  #pragma unroll
  for (int k = lane; k < H_SZ; k += 64) acc += h1[(long)b * H_SZ + k] * wlin[k];
  #pragma unroll
  for (int off = 32; off; off >>= 1) acc += __shfl_down(acc, off);
  if (lane == 0) out[b] = acc + blin[0];
}

extern "C" void kernel_launch(void* const* d_in, const int* in_sizes, int n_in,
                              void* d_out, int out_size, void* d_ws, size_t ws_size,
                              hipStream_t stream) {
  const float* x    = (const float*)d_in[0];
  const float* Wih0 = (const float*)d_in[1];
  const float* Whh0 = (const float*)d_in[2];
  const float* bih0 = (const float*)d_in[3];
  const float* bhh0 = (const float*)d_in[4];
  const float* Wih1 = (const float*)d_in[5];
  const float* Whh1 = (const float*)d_in[6];
  const float* bih1 = (const float*)d_in[7];
  const float* bhh1 = (const float*)d_in[8];
  const float* Wlin = (const float*)d_in[9];
  const float* blin = (const float*)d_in[10];

  // ws: 4 ping-pong h buffers of 128*512 floats (1 MB total).
  float* ws = (float*)d_ws;
  float* h0b[2] = { ws,           ws + 1 * B_SZ * H_SZ };
  float* h1b[2] = { ws + 2 * B_SZ * H_SZ, ws + 3 * B_SZ * H_SZ };

  static int attr_done = 0;   // idempotent, capture-safe (not a stream op)
  if (!attr_done) {
    hipFuncSetAttribute((const void*)gru_step,
                        hipFuncAttributeMaxDynamicSharedMemorySize,
                        (int)(LDS_FLOATS * sizeof(float)));
    attr_done = 1;
  }

  for (int s = 0; s <= T_LEN; ++s) {
    const float* h0r = h0b[s & 1];
    float*       h0w = h0b[(s + 1) & 1];
    const float* h1r = h1b[s & 1];
    float*       h1w = h1b[(s + 1) & 1];
    gru_step<<<dim3(256), dim3(256), LDS_FLOATS * sizeof(float), stream>>>(
        s, x, Wih0, Whh0, bih0, bhh0, Wih1, Whh1, bih1, bhh1,
        h0r, h0w, h1r, h1w);
  }
  // After s = T_LEN, final h1 state lives in h1b[(T_LEN + 1) & 1] = h1b[1].
  final_linear<<<dim3(B_SZ), dim3(64), 0, stream>>>(h1b[1], Wlin, blin, (float*)d_out);
}

// Round 2
// 36969.263 us; speedup vs baseline: 1.7941x; 1.7941x over previous
//
#include <hip/hip_runtime.h>
#include <hip/hip_bf16.h>
#include <math.h>

// GRU_74758200754229: 2-layer GRU (B=128, T=1024, F=256, H=512) + final linear.
// v3: per-step launches, lane=batch layout, weights in LDS (uniform broadcast
// reads), transposed k-pair-packed h state, 8 waves/WG for 2 waves/SIMD.

#define T_LEN 1024
#define B_SZ  128
#define F_IN  256
#define H_SZ  512

#define WL0_ROWLEN 768            // 512 (Whh0) + 256 (Wih0)
#define WL1_ROWLEN 1024           // 512 (Whh1) + 512 (Wih1)
#define WL0_FLOATS (12 * WL0_ROWLEN)
#define WL1_FLOATS (12 * WL1_ROWLEN)
#define XL_PITCH   257            // 256 + 1 pad -> conflict-free per-lane rows
#define XL_FLOATS  (64 * XL_PITCH)
#define RB_FLOATS  (2 * 2 * 6 * 64)
#define LDS_FLOATS (WL0_FLOATS + WL1_FLOATS + XL_FLOATS + RB_FLOATS)
#define LDS_BYTES  (LDS_FLOATS * 4)   // 157952 B <= 160 KiB

#define HB_PAIRED  (H_SZ * B_SZ)  // one h buffer: [256 kp][128 b][2] floats

// ---- inner helpers -------------------------------------------------------
// Weight rows live in LDS as [g*4 + jl][ROWLEN]; a wave (jg) uses jl=2jg,2jg+1.
// All 64 lanes read the SAME weight address -> LDS broadcast (free).

template<int RLEN>
__device__ __forceinline__ void fma8(const float (&h)[8],
                                     const float* __restrict__ wb, int jg, int wc,
                                     float (&ar)[2], float (&az)[2], float (&a2)[2])
{
  #pragma unroll
  for (int g = 0; g < 3; ++g) {
    #pragma unroll
    for (int jj = 0; jj < 2; ++jj) {
      const float* wr = wb + ((g << 2) + (jg << 1) + jj) * RLEN + wc;
      const float4 wA = *(const float4*)(wr);
      const float4 wB = *(const float4*)(wr + 4);
      float a = (g == 0) ? ar[jj] : (g == 1) ? az[jj] : a2[jj];
      a = fmaf(wA.x, h[0], a); a = fmaf(wA.y, h[1], a);
      a = fmaf(wA.z, h[2], a); a = fmaf(wA.w, h[3], a);
      a = fmaf(wB.x, h[4], a); a = fmaf(wB.y, h[5], a);
      a = fmaf(wB.z, h[6], a); a = fmaf(wB.w, h[7], a);
      if (g == 0) ar[jj] = a; else if (g == 1) az[jj] = a; else a2[jj] = a;
    }
  }
}

// src is k-pair packed: element (k,b) at (k>>1)*256 + b*2 + (k&1).
template<int RLEN>
__device__ __forceinline__ void dot_g(const float* __restrict__ src, int b,
                                      const float* __restrict__ wb, int jg,
                                      int wcol0, int kbeg, int kend,
                                      float (&ar)[2], float (&az)[2], float (&a2)[2])
{
  const float* sp = src + (b << 1);
  #pragma unroll 2
  for (int k = kbeg; k < kend; k += 8) {
    const int kp = k >> 1;
    float h[8];
    #pragma unroll
    for (int i = 0; i < 4; ++i) {
      const float2 q = *(const float2*)(sp + (long)(kp + i) * (B_SZ * 2));
      h[2 * i]     = q.x;
      h[2 * i + 1] = q.y;
    }
    fma8<RLEN>(h, wb, jg, wcol0 + (k - kbeg), ar, az, a2);
  }
}

__device__ __forceinline__ void dot_x(const float* __restrict__ xrow,
                                      const float* __restrict__ wb, int jg,
                                      float (&ar)[2], float (&az)[2], float (&a2)[2])
{
  #pragma unroll 2
  for (int k = 0; k < F_IN; k += 8) {
    float h[8];
    #pragma unroll
    for (int i = 0; i < 8; ++i) h[i] = xrow[k + i];
    fma8<WL0_ROWLEN>(h, wb, jg, 512 + k, ar, az, a2);
  }
}

// ---- main per-step kernel ------------------------------------------------
// Grid 256 = (b-half 0..1) x (j-quad 0..127). Block 512 = 8 waves:
// wave = (L = w>>2, jg = (w>>1)&1, kh = w&1); lanes = 64 batches.
// SIMD i gets waves i and i+4 -> one L0 (2304 FMA) + one L1 (3072 FMA): balanced.

__global__ void __launch_bounds__(512, 2)
gru_step(int s,
         const float* __restrict__ x,
         const float* __restrict__ Wih0, const float* __restrict__ Whh0,
         const float* __restrict__ bih0, const float* __restrict__ bhh0,
         const float* __restrict__ Wih1, const float* __restrict__ Whh1,
         const float* __restrict__ bih1, const float* __restrict__ bhh1,
         const float* __restrict__ h0p, float* __restrict__ h0w,
         const float* __restrict__ h1p, float* __restrict__ h1w)
{
  extern __shared__ float lds[];
  float* wl0 = lds;
  float* wl1 = wl0 + WL0_FLOATS;
  float* xl  = wl1 + WL1_FLOATS;
  float* rb  = xl  + XL_FLOATS;

  const int tid  = threadIdx.x;
  const int wave = tid >> 6;
  const int lane = tid & 63;
  const int bh = blockIdx.x >> 7;
  const int jq = blockIdx.x & 127;
  const int j0 = jq << 2;
  const int b0 = bh << 6;
  const int b  = b0 + lane;

  const bool l0_act = (s < T_LEN);
  const bool l1_act = (s >= 1);

  // ---------------- staging (all threads, uniform conditions) -------------
  if (l0_act) {
    // Whh0 rows -> wl0[r][0..511]
    for (int i = tid; i < 12 * 128; i += 512) {
      const int r = i >> 7, k4 = (i & 127) << 2;
      const int g = r >> 2, jl = r & 3;
      *(float4*)(wl0 + r * WL0_ROWLEN + k4) =
        *(const float4*)(Whh0 + (long)((g << 9) + j0 + jl) * H_SZ + k4);
    }
    // Wih0 rows -> wl0[r][512..767]
    for (int i = tid; i < 12 * 64; i += 512) {
      const int r = i >> 6, k4 = (i & 63) << 2;
      const int g = r >> 2, jl = r & 3;
      *(float4*)(wl0 + r * WL0_ROWLEN + 512 + k4) =
        *(const float4*)(Wih0 + (long)((g << 9) + j0 + jl) * F_IN + k4);
    }
    // x_t tile [64 b][256 k] -> xl (scalar, conflict-free both sides)
    for (int i = tid; i < 64 * 256; i += 512) {
      const int bb = i >> 8, k = i & 255;
      xl[bb * XL_PITCH + k] =
        x[(long)(b0 + bb) * (T_LEN * F_IN) + (long)s * F_IN + k];
    }
  }
  if (l1_act) {
    for (int i = tid; i < 12 * 128; i += 512) {
      const int r = i >> 7, k4 = (i & 127) << 2;
      const int g = r >> 2, jl = r & 3;
      *(float4*)(wl1 + r * WL1_ROWLEN + k4) =
        *(const float4*)(Whh1 + (long)((g << 9) + j0 + jl) * H_SZ + k4);
      *(float4*)(wl1 + r * WL1_ROWLEN + 512 + k4) =
        *(const float4*)(Wih1 + (long)((g << 9) + j0 + jl) * H_SZ + k4);
    }
  }
  __syncthreads();

  const int L  = wave >> 2;
  const int kh = wave & 1;
  const int jg = (wave >> 1) & 1;

  float ar[2]  = {0.f, 0.f}, az[2]  = {0.f, 0.f};
  float ahn[2] = {0.f, 0.f}, axn[2] = {0.f, 0.f};

  if (L == 0) {
    if (l0_act) {
      if (kh == 0) {
        if (s > 0) dot_g<WL0_ROWLEN>(h0p, b, wl0, jg, 0, 0, 384, ar, az, ahn);
      } else {
        if (s > 0) dot_g<WL0_ROWLEN>(h0p, b, wl0, jg, 384, 384, 512, ar, az, ahn);
        dot_x(xl + lane * XL_PITCH, wl0, jg, ar, az, axn);
      }
    }
  } else {
    if (l1_act) {
      if (kh == 0) {
        if (s > 1) dot_g<WL1_ROWLEN>(h1p, b, wl1, jg, 0, 0, 512, ar, az, ahn);
      } else {
        // input projection: y = layer-0 output at t=s-1 (== h0p buffer)
        dot_g<WL1_ROWLEN>(h0p, b, wl1, jg, 512, 0, 512, ar, az, axn);
      }
    }
  }

  // ---------------- kh-half reduction + epilogue --------------------------
  float* rbw = rb + ((L << 1) + jg) * 6 * 64;
  if (kh == 0) {
    #pragma unroll
    for (int jj = 0; jj < 2; ++jj) {
      rbw[(jj * 3 + 0) * 64 + lane] = ar[jj];
      rbw[(jj * 3 + 1) * 64 + lane] = az[jj];
      rbw[(jj * 3 + 2) * 64 + lane] = ahn[jj];
    }
  }
  __syncthreads();
  if (kh == 1 && (L ? l1_act : l0_act)) {
    const float* bi  = L ? bih1 : bih0;
    const float* bhh = L ? bhh1 : bhh0;
    const float* hp  = L ? h1p : h0p;
    float*       hw  = L ? h1w : h0w;
    const bool hprev_valid = L ? (s > 1) : (s > 0);
    // j pair (j0+2jg, j0+2jg+1) shares one k-pair slot -> float2 store
    const int jpair = (j0 + (jg << 1)) >> 1;
    float2 hv = make_float2(0.f, 0.f);
    if (hprev_valid) hv = *(const float2*)(hp + (long)jpair * (B_SZ * 2) + (b << 1));
    float2 ho;
    #pragma unroll
    for (int jj = 0; jj < 2; ++jj) {
      const int j = j0 + (jg << 1) + jj;
      const float pr  = ar[jj]  + rbw[(jj * 3 + 0) * 64 + lane] + bi[j] + bhh[j];
      const float pz  = az[jj]  + rbw[(jj * 3 + 1) * 64 + lane] + bi[H_SZ + j] + bhh[H_SZ + j];
      const float phn = ahn[jj] + rbw[(jj * 3 + 2) * 64 + lane] + bhh[2 * H_SZ + j];
      const float pxn = axn[jj] + bi[2 * H_SZ + j];
      const float rg = 1.f / (1.f + __expf(-pr));
      const float zg = 1.f / (1.f + __expf(-pz));
      const float ng = tanhf(pxn + rg * phn);
      const float hprev = jj ? hv.y : hv.x;
      const float hnew = (1.f - zg) * ng + zg * hprev;
      if (jj) ho.y = hnew; else ho.x = hnew;
    }
    *(float2*)(hw + (long)jpair * (B_SZ * 2) + (b << 1)) = ho;
  }
}

// out[b] = sum_j h1T[j][b] * wlin[j] + blin ; h1T is k-pair packed.
__global__ void __launch_bounds__(128)
final_linear(const float* __restrict__ h1T, const float* __restrict__ wlin,
             const float* __restrict__ blin, float* __restrict__ out)
{
  const int b = threadIdx.x;   // 0..127
  float acc = 0.f;
  #pragma unroll 8
  for (int jp = 0; jp < H_SZ / 2; ++jp) {
    const float2 q = *(const float2*)(h1T + (long)jp * (B_SZ * 2) + (b << 1));
    acc = fmaf(q.x, wlin[2 * jp], acc);
    acc = fmaf(q.y, wlin[2 * jp + 1], acc);
  }
  out[b] = acc + blin[0];
}

extern "C" void kernel_launch(void* const* d_in, const int* in_sizes, int n_in,
                              void* d_out, int out_size, void* d_ws, size_t ws_size,
                              hipStream_t stream) {
  const float* x    = (const float*)d_in[0];
  const float* Wih0 = (const float*)d_in[1];
  const float* Whh0 = (const float*)d_in[2];
  const float* bih0 = (const float*)d_in[3];
  const float* bhh0 = (const float*)d_in[4];
  const float* Wih1 = (const float*)d_in[5];
  const float* Whh1 = (const float*)d_in[6];
  const float* bih1 = (const float*)d_in[7];
  const float* bhh1 = (const float*)d_in[8];
  const float* Wlin = (const float*)d_in[9];
  const float* blin = (const float*)d_in[10];

  // ws: 4 h buffers (k-pair packed transposed), 1 MB total.
  float* ws = (float*)d_ws;
  float* h0b[2] = { ws,                ws + 1 * HB_PAIRED };
  float* h1b[2] = { ws + 2 * HB_PAIRED, ws + 3 * HB_PAIRED };

  static int attr_done = 0;   // idempotent, capture-safe (not a stream op)
  if (!attr_done) {
    hipFuncSetAttribute((const void*)gru_step,
                        hipFuncAttributeMaxDynamicSharedMemorySize, LDS_BYTES);
    attr_done = 1;
  }

  for (int s = 0; s <= T_LEN; ++s) {
    const int rp = s & 1, wp = rp ^ 1;
    gru_step<<<dim3(256), dim3(512), LDS_BYTES, stream>>>(
        s, x, Wih0, Whh0, bih0, bhh0, Wih1, Whh1, bih1, bhh1,
        h0b[rp], h0b[wp], h1b[rp], h1b[wp]);
  }
  // L1 @ t=1023 computed at s=1024, written to parity wp(1024)=1.
  final_linear<<<dim3(1), dim3(128), 0, stream>>>(h1b[1], Wlin, blin, (float*)d_out);
}